// Round 10
// baseline (116.212 us; speedup 1.0000x reference)
//
#include <hip/hip_runtime.h>
#include <stdint.h>

#define NROWS 8192
#define DIM   2048
#define MARGIN 2.0f
#define SCALEQ (127.0f / 6.0f)          // quantize scale
#define S2     ((6.0f / 127.0f) * (6.0f / 127.0f))   // dequant^2

// ---- 256x256 i8 tile kernel geometry (byte units) ----
#define BT2     256
#define BKB     128                      // K-bytes (=elems) per tile-step
#define NKT     (DIM / BKB)              // 16 K-tiles
#define NT2     (NROWS / BT2)            // 32 tile-rows
#define NTILES2 (NT2 * (NT2 + 1) / 2)    // 528 upper-tri tiles
#define NQ      16                       // tiles 0..15 split into 4 row-quarters
// LDS layout (bytes): A-buf0 [0,32K) | A-buf1 [32K,64K) | B-buf0 [64K,96K) | B-buf1 [96K,128K)
#define BREG    65536

typedef __attribute__((ext_vector_type(4)))  int  int4v;    // 16B operand
typedef __attribute__((ext_vector_type(16))) int  int16v;   // 32x32 i32 acc
typedef unsigned char uchar;

// triangular decode (ti <= tj)
__device__ __forceinline__ void decode_tile(int bid, int* ti, int* tj) {
    float fn = (float)NT2 + 0.5f;
    int r = (int)(fn - sqrtf(fn * fn - 2.0f * (float)bid));
    if (r < 0) r = 0;
    if (r >= NT2) r = NT2 - 1;
    while ((r + 1) * NT2 - ((r + 1) * r) / 2 <= bid) ++r;
    while (r * NT2 - (r * (r - 1)) / 2 > bid) --r;
    *ti = r;
    *tj = r + (bid - (r * NT2 - (r * (r - 1)) / 2));
}

__device__ __forceinline__ uint pack4(float4 v) {
    int q0 = (int)__builtin_rintf(v.x * SCALEQ);
    int q1 = (int)__builtin_rintf(v.y * SCALEQ);
    int q2 = (int)__builtin_rintf(v.z * SCALEQ);
    int q3 = (int)__builtin_rintf(v.w * SCALEQ);
    q0 = min(max(q0, -127), 127); q1 = min(max(q1, -127), 127);
    q2 = min(max(q2, -127), 127); q3 = min(max(q3, -127), 127);
    return (uint)(q0 & 0xFF) | ((uint)(q1 & 0xFF) << 8) |
           ((uint)(q2 & 0xFF) << 16) | ((uint)(q3 & 0xFF) << 24);
}

// ---------------- kernel 1: fp32 -> i8 quantize + fp32 row sum of squares ---
__global__ __launch_bounds__(256) void prep_kernel(const float* __restrict__ p,
                                                   uchar* __restrict__ pb,
                                                   float* __restrict__ sq) {
    int row = blockIdx.x;
    int t = threadIdx.x;
    const float4* prow = (const float4*)(p + (size_t)row * DIM);
    uint* qrow = (uint*)(pb + (size_t)row * DIM);
    float4 a = prow[t];
    float4 b = prow[t + 256];
    float s = a.x * a.x + a.y * a.y + a.z * a.z + a.w * a.w
            + b.x * b.x + b.y * b.y + b.z * b.z + b.w * b.w;
    qrow[t] = pack4(a);
    qrow[t + 256] = pack4(b);
#pragma unroll
    for (int o = 32; o > 0; o >>= 1) s += __shfl_down(s, o, 64);
    __shared__ float wsums[4];
    int lane = t & 63, wvv = t >> 6;
    if (lane == 0) wsums[wvv] = s;
    __syncthreads();
    if (t == 0) sq[row] = wsums[0] + wsums[1] + wsums[2] + wsums[3];
}

// ---------------- full-path staging (templated: all offsets constant-folded)
// WHICH: 0 = A half0, 1 = A half1, 2 = B half0, 3 = B half1.
// TT >= NKT clamps to TT-2 (parity preserved, dead data, same write window).
template<int TT, int WHICH>
__device__ __forceinline__ void stage_c(const uchar* __restrict__ pb, uchar* lds,
                                        int ibase, int jbase, int tid) {
    constexpr int t   = (TT >= NKT) ? TT - 2 : TT;
    constexpr int buf = t & 1;
    constexpr int h   = WHICH & 1;
    constexpr bool isB = (WHICH >= 2);
    const int row0 = (isB ? jbase : ibase) + h * 128;
    const uchar* g0 = pb + (size_t)row0 * DIM + t * BKB;
    uchar* l0 = lds + (isB ? BREG : 0) + buf * 32768 + h * 16384;
#pragma unroll
    for (int r = 0; r < 2; ++r) {
        int row = r * 64 + (tid >> 3);
        int c8 = (tid & 7) ^ ((tid >> 3) & 7);         // pre-swizzled 16B slot
        const uchar* g = g0 + (size_t)row * DIM + c8 * 16;
        uchar* l = l0 + r * 8192 + (tid >> 6) * 1024;  // wave-uniform (+lane*16 HW)
        __builtin_amdgcn_global_load_lds(
            (const __attribute__((address_space(1))) uint32_t*)g,
            (__attribute__((address_space(3))) uint32_t*)l, 16, 0, 0);
    }
}

// quarter-path runtime staging (new layout)
__device__ __forceinline__ void stage_qB(const uchar* __restrict__ pb, uchar* lds,
                                         int t, int h, int jbase, int tid) {
    if (t >= NKT) t -= 2;
    const uchar* g0 = pb + (size_t)(jbase + h * 128) * DIM + t * BKB;
    uchar* l0 = lds + BREG + (t & 1) * 32768 + h * 16384;
#pragma unroll
    for (int r = 0; r < 2; ++r) {
        int row = r * 64 + (tid >> 3);
        int c8 = (tid & 7) ^ ((tid >> 3) & 7);
        const uchar* g = g0 + (size_t)row * DIM + c8 * 16;
        uchar* l = l0 + r * 8192 + (tid >> 6) * 1024;
        __builtin_amdgcn_global_load_lds(
            (const __attribute__((address_space(1))) uint32_t*)g,
            (__attribute__((address_space(3))) uint32_t*)l, 16, 0, 0);
    }
}
__device__ __forceinline__ void stage_qA(const uchar* __restrict__ pb, uchar* lds,
                                         int t, int ibase, int tid) {
    if (t >= NKT) t -= 2;
    const uchar* g0 = pb + (size_t)ibase * DIM + t * BKB;
    uchar* l0 = lds + (t & 1) * 32768;
    int row = tid >> 3;                                // 0..63
    int c8 = (tid & 7) ^ ((tid >> 3) & 7);
    const uchar* g = g0 + (size_t)row * DIM + c8 * 16;
    uchar* l = l0 + (tid >> 6) * 1024;
    __builtin_amdgcn_global_load_lds(
        (const __attribute__((address_space(1))) uint32_t*)g,
        (__attribute__((address_space(3))) uint32_t*)l, 16, 0, 0);
}

#define BARF()   do { __builtin_amdgcn_s_barrier(); \
                      asm volatile("" ::: "memory"); } while (0)
#define WAITL()  asm volatile("s_waitcnt lgkmcnt(0)" ::: "memory")
#define WAITV8() asm volatile("s_waitcnt vmcnt(8)" ::: "memory")
#define WAITV5() asm volatile("s_waitcnt vmcnt(5)" ::: "memory")
#define WAITV0() asm volatile("s_waitcnt vmcnt(0)" ::: "memory")
#define PRIO1()  __builtin_amdgcn_s_setprio(1)
#define PRIO0()  __builtin_amdgcn_s_setprio(0)
#define SB0()    __builtin_amdgcn_sched_barrier(0)

// precomputed-address ds_reads: addr = comb[s] (VGPR) + compile-time offset
#define RD_A_C(MH, BUFO)                                                       \
    _Pragma("unroll") for (int mt = 0; mt < 2; ++mt)                           \
    _Pragma("unroll") for (int s = 0; s < 4; ++s)                              \
        af[mt][s] = *(const int4v*)&lds[acomb[s] +                             \
                     (((MH) * 2 + mt) * 4096 + (BUFO))];

#define RD_B_C(DST, NH, BUFO)                                                  \
    _Pragma("unroll") for (int s = 0; s < 4; ++s)                              \
        DST[s] = *(const int4v*)&lds[bcomb[s] + ((NH) * 4096 + (BUFO))];

#define MFMAQ(MH, BF, NH)                                                      \
    _Pragma("unroll") for (int mt = 0; mt < 2; ++mt)                           \
    _Pragma("unroll") for (int s = 0; s < 4; ++s)                              \
        acc[(MH) * 2 + mt][NH] = __builtin_amdgcn_mfma_i32_32x32x32_i8(        \
            af[mt][s], BF[s], acc[(MH) * 2 + mt][NH], 0, 0, 0);

// FULL step: R6's proven 4-phase/8-barrier schedule, zero per-step addr VALU.
// Stages for T+2 issue in P3 (B halves) / P4 (A halves); WAITV8 boundary.
#define STEPF(T)                                                               \
    {                                                                          \
        constexpr int BUFO = ((T) & 1) * 32768;                                \
        RD_A_C(0, BUFO);                                                       \
        RD_B_C(bf0, 0, BUFO);                                                  \
        BARF(); WAITL(); SB0();                                                \
        PRIO1(); MFMAQ(0, bf0, 0); PRIO0();                                    \
        BARF();                                                                \
        RD_B_C(bf1, 1, BUFO);                                                  \
        BARF(); WAITL(); SB0();                                                \
        PRIO1(); MFMAQ(0, bf1, 1); PRIO0();                                    \
        BARF();                                                                \
        RD_A_C(1, BUFO);                                                       \
        stage_c<(T) + 2, 2>(pb, lds, ibase, jbase, tid);                       \
        stage_c<(T) + 2, 3>(pb, lds, ibase, jbase, tid);                       \
        BARF(); WAITL(); SB0();                                                \
        PRIO1(); MFMAQ(1, bf0, 0); PRIO0();                                    \
        BARF();                                                                \
        stage_c<(T) + 2, 0>(pb, lds, ibase, jbase, tid);                       \
        stage_c<(T) + 2, 1>(pb, lds, ibase, jbase, tid);                       \
        PRIO1(); MFMAQ(1, bf1, 1); PRIO0();                                    \
        WAITV8(); BARF();                                                      \
    }

// QUARTER step (64x256 strip; wave w owns cols w*32..w*32+31)
#define STEP_Q(T)                                                              \
    {                                                                          \
        const int qb = ((T) & 1) * 32768;                                      \
        _Pragma("unroll") for (int mt = 0; mt < 2; ++mt)                       \
        _Pragma("unroll") for (int s = 0; s < 4; ++s)                          \
            aq[mt][s] = *(const int4v*)&lds[aqc[s] + mt * 4096 + qb];          \
        _Pragma("unroll") for (int s = 0; s < 4; ++s)                          \
            bq[s] = *(const int4v*)&lds[bqc[s] + qb];                          \
        WAITL(); SB0();                                                        \
        PRIO1();                                                               \
        _Pragma("unroll") for (int s = 0; s < 4; ++s)                          \
        _Pragma("unroll") for (int mt = 0; mt < 2; ++mt)                       \
            accq[mt] = __builtin_amdgcn_mfma_i32_32x32x32_i8(                  \
                aq[mt][s], bq[s], accq[mt], 0, 0, 0);                          \
        PRIO0();                                                               \
        BARF();                                                                \
        stage_qA(pb, lds, (T) + 2, ibase, tid);                                \
        stage_qB(pb, lds, (T) + 2, 0, jbase, tid);                             \
        stage_qB(pb, lds, (T) + 2, 1, jbase, tid);                             \
        WAITV5(); BARF();                                                      \
    }

// ---------------- kernel 2: triangular Gram + fused loss --------------------
// Grid = 64 quarter blocks (tiles 0..15 x 4 row-quarters, first) + 512 fulls.
// 512 threads, 8 waves (2 waves/SIMD).
__global__ __launch_bounds__(512) void tile2_kernel(
    const uchar* __restrict__ pb, const float* __restrict__ sq,
    const int* __restrict__ gt, double* __restrict__ accum) {

    __shared__ uchar lds[131072];   // 128 KiB (layout per #define BREG)
    __shared__ float wsum[8];

    const int bx = (int)blockIdx.x;
    const bool is_q = (bx < 4 * NQ);
    int bid, qq = 0;
    if (is_q) { bid = bx >> 2; qq = bx & 3; }
    else { int f = bx - 4 * NQ; bid = NQ + ((f & 7) << 6) + (f >> 3); } // 512=8*64

    int ti, tj;
    decode_tile(bid, &ti, &tj);

    const int tid = threadIdx.x;
    const int lane = tid & 63;
    const int kh = lane >> 5;            // K-half within a 32-wide slice
    const int wv = tid >> 6;             // wave 0..7
    const int wr = wv >> 2;              // full: row half (128 rows)
    const int wc = wv & 3;               // full: col group (64 cols)
    const int jbase = tj * BT2;
    const int ibase = ti * BT2 + (is_q ? qq * 64 : 0);

    const float invd = 1.0f / (float)DIM;
    float lsum = 0.f;

    if (!is_q) {
        int16v acc[4][2] = {};
        int4v af[2][4];
        int4v bf0[4], bf1[4];

        // precomputed per-lane LDS byte addresses (buf0); buffer/mtile deltas
        // are compile-time DS offsets.
        int acomb[4], bcomb[4];
#pragma unroll
        for (int s = 0; s < 4; ++s) {
            int slot = ((2 * s + kh) ^ (lane & 7)) * 16;
            acomb[s] = (wr * 128 + (lane & 31)) * 128 + slot;
            bcomb[s] = BREG + (wc * 64 + (lane & 31)) * 128 + slot;
        }

        // prologue: tiles 0,1 fully issued (16 insts); vmcnt(8) -> tile0 resident.
        stage_c<0, 2>(pb, lds, ibase, jbase, tid);
        stage_c<0, 3>(pb, lds, ibase, jbase, tid);
        stage_c<0, 0>(pb, lds, ibase, jbase, tid);
        stage_c<0, 1>(pb, lds, ibase, jbase, tid);
        stage_c<1, 2>(pb, lds, ibase, jbase, tid);
        stage_c<1, 3>(pb, lds, ibase, jbase, tid);
        stage_c<1, 0>(pb, lds, ibase, jbase, tid);
        stage_c<1, 1>(pb, lds, ibase, jbase, tid);
        WAITV8();
        BARF();

        STEPF(0);  STEPF(1);  STEPF(2);  STEPF(3);
        STEPF(4);  STEPF(5);  STEPF(6);  STEPF(7);
        STEPF(8);  STEPF(9);  STEPF(10); STEPF(11);
        STEPF(12); STEPF(13); STEPF(14); STEPF(15);

        WAITV0();
        BARF();

        // fused epilogue: dequant -> d2 -> contrastive term -> weighted sum
        int j0 = jbase + wc * 64 + (lane & 31);
        float sqj[2]; int gj[2];
#pragma unroll
        for (int n = 0; n < 2; ++n) { int j = j0 + n * 32; sqj[n] = sq[j]; gj[n] = gt[j]; }
        const float wb = (ti != tj) ? 2.0f : 1.0f;
#pragma unroll
        for (int mi = 0; mi < 4; ++mi) {
#pragma unroll
            for (int q = 0; q < 4; ++q) {
#pragma unroll
                for (int rr = 0; rr < 4; ++rr) {
                    int i = ibase + wr * 128 + mi * 32 + rr + 8 * q + 4 * kh;
                    float sqi = sq[i];
                    int gi = gt[i];
#pragma unroll
                    for (int n = 0; n < 2; ++n) {
                        int j = j0 + n * 32;
                        float dot = S2 * (float)acc[mi][n][q * 4 + rr];
                        float d2 = fmaxf(sqi + sqj[n] - 2.0f * dot, 0.0f) * invd;
                        float term = (gi == gj[n]) ? d2 : fmaxf(MARGIN - d2, 0.0f);
                        float w = wb;
                        if (ti == tj && i == j) w = 2.0f;
                        lsum += w * term;
                    }
                }
            }
        }
    } else {
        int16v accq[2] = {};
        int4v aq[2][4], bq[4];

        int aqc[4], bqc[4];
#pragma unroll
        for (int s = 0; s < 4; ++s) {
            int slot = ((2 * s + kh) ^ (lane & 7)) * 16;
            aqc[s] = (lane & 31) * 128 + slot;                       // A rows 0..63
            bqc[s] = BREG + (wv * 32 + (lane & 31)) * 128 + slot;    // B strip
        }

        // prologue: tiles 0,1 (5 insts each); vmcnt(5) -> tile0 resident.
        stage_qA(pb, lds, 0, ibase, tid);
        stage_qB(pb, lds, 0, 0, jbase, tid);
        stage_qB(pb, lds, 0, 1, jbase, tid);
        stage_qA(pb, lds, 1, ibase, tid);
        stage_qB(pb, lds, 1, 0, jbase, tid);
        stage_qB(pb, lds, 1, 1, jbase, tid);
        WAITV5();
        BARF();

#pragma unroll 1
        for (int s0 = 0; s0 < NKT; s0 += 2) {
            STEP_Q(s0);
            STEP_Q(s0 + 1);
        }
        WAITV0();
        BARF();

        int j = jbase + wv * 32 + (lane & 31);
        float sqj = sq[j];
        int gj = gt[j];
        const float wb = (ti != tj) ? 2.0f : 1.0f;
#pragma unroll
        for (int mt = 0; mt < 2; ++mt) {
#pragma unroll
            for (int q = 0; q < 4; ++q) {
#pragma unroll
                for (int rr = 0; rr < 4; ++rr) {
                    int i = ibase + mt * 32 + rr + 8 * q + 4 * kh;
                    float dot = S2 * (float)accq[mt][q * 4 + rr];
                    float d2 = fmaxf(sq[i] + sqj - 2.0f * dot, 0.0f) * invd;
                    float term = (gt[i] == gj) ? d2 : fmaxf(MARGIN - d2, 0.0f);
                    float w = wb;
                    if (ti == tj && i == j) w = 2.0f;
                    lsum += w * term;
                }
            }
        }
    }

#pragma unroll
    for (int o = 32; o > 0; o >>= 1) lsum += __shfl_down(lsum, o, 64);
    if (lane == 0) wsum[wv] = lsum;
    __syncthreads();
    if (tid == 0) {
        float s = 0.f;
#pragma unroll
        for (int w = 0; w < 8; ++w) s += wsum[w];
        atomicAdd(accum, (double)s);
    }
}

// ---------------- kernel 3: finalize ----------------------------------------
__global__ void finalize_kernel(const double* __restrict__ accum,
                                float* __restrict__ out) {
    if (threadIdx.x == 0)
        out[0] = (float)(accum[0] * (1.0 / ((double)NROWS * (double)(NROWS - 1))));
}

extern "C" void kernel_launch(void* const* d_in, const int* in_sizes, int n_in,
                              void* d_out, int out_size, void* d_ws, size_t ws_size,
                              hipStream_t stream) {
    (void)in_sizes; (void)n_in; (void)out_size; (void)ws_size;
    const float* p = (const float*)d_in[0];
    const int* gt = (const int*)d_in[1];
    float* out = (float*)d_out;

    // ws layout: pb 16MB i8 | sq 32KB | accum 8B
    uchar* pb = (uchar*)d_ws;
    size_t off = (size_t)NROWS * DIM;                   // 16,777,216
    float* sq = (float*)((char*)d_ws + off);
    off += (size_t)NROWS * sizeof(float);               // +32 KB
    double* accum = (double*)((char*)d_ws + off);

    (void)hipMemsetAsync(accum, 0, sizeof(double), stream);
    prep_kernel<<<NROWS, 256, 0, stream>>>(p, pb, sq);
    tile2_kernel<<<4 * NQ + 512, 512, 0, stream>>>(pb, sq, gt, accum);
    finalize_kernel<<<1, 64, 0, stream>>>(accum, out);
}